// Round 5
// baseline (87.829 us; speedup 1.0000x reference)
//
#include <hip/hip_runtime.h>

typedef float v2f __attribute__((ext_vector_type(2)));
typedef float v4f __attribute__((ext_vector_type(4)));

#define EPS 1e-7f
#define SPW 66   // LDS row stride in v2f: 528 B = 33*16 (rows b128-aligned)

// mantissa_map: (|v|+eps) -> mantissa m in [1,2); result = m>=1.5 ? m/2 : m  -> [0.75,1.5)
__device__ __forceinline__ float mant_map(float v) {
    float a = fabsf(v) + EPS;
    unsigned int bi = __float_as_uint(a);
    float m = __uint_as_float((bi & 0x007FFFFFu) | 0x3F800000u);
    return (m >= 1.5f) ? 0.5f * m : m;
}

// R5: one block per (b,c) plane, (32,8)=256 threads, grid (192,4).
// Thread (lx,ty): out cols {2lx,2lx+1} (store-guarded to lx<28), rows ty*7..+6.
// out = sum_taps u*B + v*C, u=x, v=x/M1, B=w/M2, C=B*(M2-1).
//
// Weights live in SGPRs: lane t (t<49) of each wave computes tap t's {B,C};
// compile-time v_readlane broadcasts to SGPRs; inner loop = v_fma_f32 with the
// SGPR as the one legal scalar source. Taps split by column (j<4 | j>=4) so
// peak weight-SGPR count is 56.
//
// R4 failed (absmax 8.4): readlanes sat inside divergent `if(lx<28)`; LLVM sank
// the Bv/Cv computation into the branch, so lanes 28..31 (taps 28..31) never
// computed values -> readlane poison. R5: the whole compute body is wave-uniform
// (x0 clamps lx to 27; duplicated work, zero extra issue cost); only the store
// is guarded. Bv/Cv pinned at full exec as insurance.
__global__ __launch_bounds__(256, 3) void wconv_kernel(const float* __restrict__ x,
                                                       const float* __restrict__ w,
                                                       float* __restrict__ out) {
    __shared__ v2f sp[62][SPW];  // LDS row r = input row r-3; pair k = input col k-3

    const int lx = threadIdx.x;   // 0..31
    const int ty = threadIdx.y;   // 0..7
    const int tid = ty * 32 + lx;
    const int lane = tid & 63;
    const int c = blockIdx.x;
    const int b = blockIdx.y;

    const long plane = (long)(b * 192 + c) * 3136;
    const float* xp = x + plane;

    // --- per-wave weight prep at FULL exec: lane t holds tap t's {B,C} ---
    float Bv, Cv;
    {
        int lv = (lane < 49) ? lane : 48;         // clamp: avoid OOB load
        float wv = w[c * 49 + lv];
        float M2 = mant_map(wv);
        Bv = wv / M2;
        Cv = Bv * (M2 - 1.0f);
    }
    asm volatile("" : "+v"(Bv), "+v"(Cv));        // materialize at full exec (anti-sink)

    // --- halo zero: rows 0..2 and 59..61 full width ---
    for (int t = tid; t < 3 * SPW; t += 256) {
        ((v2f*)sp)[t] = (v2f){0.f, 0.f};
        ((v2f*)sp)[59 * SPW + t] = (v2f){0.f, 0.f};
    }
    // side halo of the 56 real rows: pairs 0,1,2 (cols -3..-1) and 59,60,61 (56..58)
    for (int t = tid; t < 336; t += 256) {
        int r = t / 6, k = t % 6;
        int col = (k < 3) ? k : 56 + k;
        sp[3 + r][col] = (v2f){0.f, 0.f};
    }

    // --- interior staging: 56 rows x 14 quads = 784 tasks ---
    {
        const int t0 = tid, t1 = tid + 256, t2 = tid + 512;
        v4f u0 = *(const v4f*)(xp + (t0 / 14) * 56 + (t0 % 14) * 4);
        v4f u1 = *(const v4f*)(xp + (t1 / 14) * 56 + (t1 % 14) * 4);
        v4f u2 = *(const v4f*)(xp + (t2 / 14) * 56 + (t2 % 14) * 4);
        v4f u3;
        if (tid < 16) u3 = *(const v4f*)(xp + ((tid + 768) / 14) * 56 + ((tid + 768) % 14) * 4);

        auto stage = [&](int t, v4f u4) {
            v2f* dst = &sp[3 + t / 14][3 + (t % 14) * 4];
            dst[0] = (v2f){u4.x, u4.x * __builtin_amdgcn_rcpf(mant_map(u4.x))};
            dst[1] = (v2f){u4.y, u4.y * __builtin_amdgcn_rcpf(mant_map(u4.y))};
            dst[2] = (v2f){u4.z, u4.z * __builtin_amdgcn_rcpf(mant_map(u4.z))};
            dst[3] = (v2f){u4.w, u4.w * __builtin_amdgcn_rcpf(mant_map(u4.w))};
        };
        stage(t0, u0);
        stage(t1, u1);
        stage(t2, u2);
        if (tid < 16) stage(tid + 768, u3);
    }
    __syncthreads();

#define RL(val, t) __uint_as_float(__builtin_amdgcn_readlane(__float_as_uint(val), (t)))

    // --- compute: WAVE-UNIFORM body (lanes 28..31 duplicate lane 27) ---
    {
        const int x0 = ((lx < 28) ? lx : 27) * 2;  // pair base; pair x0+k = input col 2lx-3+k
        const int rb = ty * 7;                     // output row base

        float a0x[7], a0y[7], a1x[7], a1y[7];
        #pragma unroll
        for (int r = 0; r < 7; ++r) { a0x[r] = a0y[r] = a1x[r] = a1y[r] = 0.f; }

        // ---- Pass A: tap cols j=0..3 (28 taps -> 56 SGPRs), pairs x0..x0+4 ----
        {
            float sB[28], sC[28];
            #pragma unroll
            for (int i = 0; i < 7; ++i)
                #pragma unroll
                for (int j = 0; j < 4; ++j) {
                    sB[i * 4 + j] = RL(Bv, i * 7 + j);
                    sC[i * 4 + j] = RL(Cv, i * 7 + j);
                }
            #pragma unroll
            for (int ir = 0; ir < 13; ++ir) {
                const v2f* row_ = &sp[rb + ir][0];
                v4f q0 = *(const v4f*)&row_[x0];      // pairs x0, x0+1
                v4f q1 = *(const v4f*)&row_[x0 + 2];  // pairs x0+2, x0+3
                v2f q2 = row_[x0 + 4];                // pair  x0+4
                float pu[5] = {q0.x, q0.z, q1.x, q1.z, q2.x};
                float pv[5] = {q0.y, q0.w, q1.y, q1.w, q2.y};
                #pragma unroll
                for (int ry = 0; ry < 7; ++ry) {
                    const int i = ir - ry;            // weight row, compile-time
                    if (i >= 0 && i <= 6) {
                        #pragma unroll
                        for (int j = 0; j < 4; ++j) {
                            const int t = i * 4 + j;
                            a0x[ry] = fmaf(pu[j],     sB[t], a0x[ry]);  // v_fma_f32, SGPR src
                            a0y[ry] = fmaf(pv[j],     sC[t], a0y[ry]);
                            a1x[ry] = fmaf(pu[j + 1], sB[t], a1x[ry]);
                            a1y[ry] = fmaf(pv[j + 1], sC[t], a1y[ry]);
                        }
                    }
                }
            }
        }

        __builtin_amdgcn_sched_barrier(0);   // keep pass-B readlanes out of pass A

        // ---- Pass B: tap cols j=4..6 (21 taps -> 42 SGPRs), pairs x0+4..x0+7 ----
        {
            float sB[21], sC[21];
            #pragma unroll
            for (int i = 0; i < 7; ++i)
                #pragma unroll
                for (int j = 4; j < 7; ++j) {
                    sB[i * 3 + (j - 4)] = RL(Bv, i * 7 + j);
                    sC[i * 3 + (j - 4)] = RL(Cv, i * 7 + j);
                }
            #pragma unroll
            for (int ir = 0; ir < 13; ++ir) {
                const v2f* row_ = &sp[rb + ir][0];
                v4f q2 = *(const v4f*)&row_[x0 + 4];  // pairs x0+4, x0+5
                v4f q3 = *(const v4f*)&row_[x0 + 6];  // pairs x0+6, x0+7
                float pu[4] = {q2.x, q2.z, q3.x, q3.z};
                float pv[4] = {q2.y, q2.w, q3.y, q3.w};
                #pragma unroll
                for (int ry = 0; ry < 7; ++ry) {
                    const int i = ir - ry;
                    if (i >= 0 && i <= 6) {
                        #pragma unroll
                        for (int j = 4; j < 7; ++j) {
                            const int t = i * 3 + (j - 4);
                            a0x[ry] = fmaf(pu[j - 4], sB[t], a0x[ry]);
                            a0y[ry] = fmaf(pv[j - 4], sC[t], a0y[ry]);
                            a1x[ry] = fmaf(pu[j - 3], sB[t], a1x[ry]);
                            a1y[ry] = fmaf(pv[j - 3], sC[t], a1y[ry]);
                        }
                    }
                }
            }
        }
#undef RL

        // --- store: the ONLY divergent region ---
        if (lx < 28) {
            #pragma unroll
            for (int ry = 0; ry < 7; ++ry) {
                float2 o = make_float2(a0x[ry] + a0y[ry], a1x[ry] + a1y[ry]);
                *(float2*)&out[plane + (rb + ry) * 56 + x0] = o;
            }
        }
    }
}

extern "C" void kernel_launch(void* const* d_in, const int* in_sizes, int n_in,
                              void* d_out, int out_size, void* d_ws, size_t ws_size,
                              hipStream_t stream) {
    const float* x = (const float*)d_in[0];   // (4,192,56,56) fp32
    const float* w = (const float*)d_in[1];   // (192,1,7,7) fp32
    float* out = (float*)d_out;

    hipLaunchKernelGGL(wconv_kernel, dim3(192, 4), dim3(32, 8), 0, stream, x, w, out);
}

// Round 6
// 71.305 us; speedup vs baseline: 1.2317x; 1.2317x over previous
//
#include <hip/hip_runtime.h>

typedef float v2f __attribute__((ext_vector_type(2)));
typedef float v4f __attribute__((ext_vector_type(4)));

#define EPS 1e-7f
#define SPW 66   // LDS row stride in v2f: 528 B = 33*16 (rows stay b128-aligned)

// mantissa_map: (|v|+eps) -> mantissa m in [1,2); result = m>=1.5 ? m/2 : m  -> [0.75,1.5)
__device__ __forceinline__ float mant_map(float v) {
    float a = fabsf(v) + EPS;
    unsigned int bi = __float_as_uint(a);
    float m = __uint_as_float((bi & 0x007FFFFFu) | 0x3F800000u);
    return (m >= 1.5f) ? 0.5f * m : m;
}

// R6: small high-residency blocks. Grid (192, 4, 7), block (32,4)=128 thr.
// Block (c, b, z) computes output rows y0=8z .. y0+7 of plane (b,c).
// LDS: 14 input rows x 66 col-pairs = 7.4 KB -> 10-16 blocks/CU (20-32 waves)
// vs R2-R5's 33KB whole-plane blocks (~1-2 blocks/CU, latency-exposed).
// Thread (lx,ty): out cols {2lx,2lx+1} (lx clamped to 27, store-guarded),
// out rows y0+2ty, y0+2ty+1.
// out = sum_taps u*B + v*C, u=x, v=x/M1, B=w/M2, C=B*(M2-1).
//
// Inner loop is weight-row-outer with a 2-row register rotation: per thread
// 49 weight ds_read_b64 (broadcast) + 32 input ds_read_b128 + 196 v_pk_fma
// (R0: 343 + 52 + 686). All indexing compile-time static (no scratch).
__global__ __launch_bounds__(128, 4) void wconv_kernel(const float* __restrict__ x,
                                                       const float* __restrict__ w,
                                                       float* __restrict__ out) {
    __shared__ v2f sp[14][SPW];  // LDS row r = input row y0-3+r; pair k = input col k-3
    __shared__ v2f swt[49];      // {B, C} per tap

    const int lx = threadIdx.x;   // 0..31
    const int ty = threadIdx.y;   // 0..3
    const int tid = ty * 32 + lx; // 0..127
    const int c = blockIdx.x;
    const int b = blockIdx.y;
    const int y0 = blockIdx.z * 8;

    const long plane = (long)(b * 192 + c) * 3136;
    const float* xp = x + plane;

    // --- fused weight prep ---
    if (tid < 49) {
        float wv = w[c * 49 + tid];
        float M2 = mant_map(wv);
        float B = wv / M2;
        swt[tid] = (v2f){B, B * (M2 - 1.0f)};
    }

    // --- side halo zero: pairs 0,1,2 (cols -3..-1) and 59,60,61 (cols 56..58) ---
    if (tid < 84) {
        int r = tid / 6, k = tid % 6;
        int col = (k < 3) ? k : 56 + k;
        sp[r][col] = (v2f){0.f, 0.f};
    }

    // --- interior staging: 14 rows x 14 quads = 196 tasks; rows outside the
    // image (z=0: g<0, z=6: g>55) stage zeros. Loads issued before writes. ---
    {
        const int t0 = tid, t1 = tid + 128;          // t1 valid if tid < 68
        const int r0 = t0 / 14, q0 = t0 % 14;
        const int r1 = t1 / 14, q1 = t1 % 14;
        const int g0 = y0 - 3 + r0, g1 = y0 - 3 + r1;

        v4f u0 = (v4f){0.f, 0.f, 0.f, 0.f}, u1 = u0;
        if (g0 >= 0 && g0 < 56) u0 = *(const v4f*)(xp + g0 * 56 + q0 * 4);
        if (t1 < 196 && g1 >= 0 && g1 < 56) u1 = *(const v4f*)(xp + g1 * 56 + q1 * 4);

        auto stage = [&](int r, int q, v4f u4) {
            v4f* dst = (v4f*)&sp[r][3 + q * 4];      // pairs 3+4q..6+4q = cols 4q..4q+3
            dst[0] = (v4f){u4.x, u4.x * __builtin_amdgcn_rcpf(mant_map(u4.x)),
                           u4.y, u4.y * __builtin_amdgcn_rcpf(mant_map(u4.y))};
            dst[1] = (v4f){u4.z, u4.z * __builtin_amdgcn_rcpf(mant_map(u4.z)),
                           u4.w, u4.w * __builtin_amdgcn_rcpf(mant_map(u4.w))};
        };
        stage(r0, q0, u0);
        if (t1 < 196) stage(r1, q1, u1);
    }
    __syncthreads();

    // --- compute: wave-uniform body (lanes 28..31 duplicate lane 27) ---
    {
        const int x0 = ((lx < 28) ? lx : 27) * 2;    // pair base; P[k] = col 2lx-3+k
        const int rb = ty * 2;                       // LDS row base (= out row offset)

        // row buffer load: pairs x0..x0+7 of LDS row R (4x ds_read_b128)
#define LOADROW(P, R)                                                   \
        {                                                               \
            const v4f* s_ = (const v4f*)&sp[(R)][x0];                   \
            v4f t0_ = s_[0], t1_ = s_[1], t2_ = s_[2], t3_ = s_[3];     \
            P[0] = (v2f){t0_.x, t0_.y}; P[1] = (v2f){t0_.z, t0_.w};     \
            P[2] = (v2f){t1_.x, t1_.y}; P[3] = (v2f){t1_.z, t1_.w};     \
            P[4] = (v2f){t2_.x, t2_.y}; P[5] = (v2f){t2_.z, t2_.w};     \
            P[6] = (v2f){t3_.x, t3_.y}; P[7] = (v2f){t3_.z, t3_.w};     \
        }

        v2f RA[8], RB[8];
        LOADROW(RA, rb);         // row rb+0 (ry0's first row)
        LOADROW(RB, rb + 1);     // row rb+1 (ry1's first row)

        v2f a00 = {0.f, 0.f}, a01 = {0.f, 0.f};   // ry0: cols 2lx, 2lx+1
        v2f a10 = {0.f, 0.f}, a11 = {0.f, 0.f};   // ry1

        // At step i: P holds LDS row rb+i (ry0), Q holds rb+i+1 (ry1).
        // 7 weight b64 broadcasts + 28 v_pk_fma per step; then rotate.
#define STEP(i, P, Q)                                                   \
        {                                                               \
            _Pragma("unroll")                                           \
            for (int j = 0; j < 7; ++j) {                               \
                v2f wc = swt[(i) * 7 + j];                              \
                a00 += P[j] * wc;  a01 += P[j + 1] * wc;                \
                a10 += Q[j] * wc;  a11 += Q[j + 1] * wc;                \
            }                                                           \
        }

        STEP(0, RA, RB) LOADROW(RA, rb + 2)
        STEP(1, RB, RA) LOADROW(RB, rb + 3)
        STEP(2, RA, RB) LOADROW(RA, rb + 4)
        STEP(3, RB, RA) LOADROW(RB, rb + 5)
        STEP(4, RA, RB) LOADROW(RA, rb + 6)
        STEP(5, RB, RA) LOADROW(RB, rb + 7)
        STEP(6, RA, RB)
#undef STEP
#undef LOADROW

        // --- store: the only divergent region ---
        if (lx < 28) {
            float2 o0 = make_float2(a00.x + a00.y, a01.x + a01.y);
            float2 o1 = make_float2(a10.x + a10.y, a11.x + a11.y);
            *(float2*)&out[plane + (y0 + rb)     * 56 + x0] = o0;
            *(float2*)&out[plane + (y0 + rb + 1) * 56 + x0] = o1;
        }
    }
}

extern "C" void kernel_launch(void* const* d_in, const int* in_sizes, int n_in,
                              void* d_out, int out_size, void* d_ws, size_t ws_size,
                              hipStream_t stream) {
    const float* x = (const float*)d_in[0];   // (4,192,56,56) fp32
    const float* w = (const float*)d_in[1];   // (192,1,7,7) fp32
    float* out = (float*)d_out;

    hipLaunchKernelGGL(wconv_kernel, dim3(192, 4, 7), dim3(32, 4), 0, stream, x, w, out);
}